// Round 1
// baseline (1159.823 us; speedup 1.0000x reference)
//
#include <hip/hip_runtime.h>
#include <math.h>

// ADIOS contrastive loss, MI355X fp32 baseline.
// Strategy: per-row inv-norms -> fused GEMM(orig x all_emb^T)+exp+rowsum -> tiny loss reduce.
// No fp32 MFMA on CDNA4, so the 86-GFLOP matmul runs on the vector ALU (157 TF peak).

#define B_ROWS 4096
#define M_MASK 4
#define D_DIM  512
#define N_COLS ((M_MASK + 1) * B_ROWS)   // 20480

#define BM 128
#define BN 128
#define BK 32
#define COLSPLIT 32
#define CHUNK (N_COLS / COLSPLIT)        // 640 = 5 tiles of BN

__device__ __forceinline__ float inv_temp(const int* __restrict__ itp) {
    int it = *itp;
    double T;
    if (it >= 300000) {
        T = 0.05;
    } else {
        double p = (double)it / 300000.0;
        T = 0.05 + 0.5 * (0.2 - 0.05) * (1.0 + cos(3.14159265358979323846 * p));
    }
    return (float)(1.0 / T);
}

// One wave per row: inv_norm[i] = 1 / max(||row_i||, 1e-12)
__global__ __launch_bounds__(256) void norm_kernel(
        const float* __restrict__ orig, const float* __restrict__ masked,
        float* __restrict__ inv) {
    int gw = blockIdx.x * 4 + (threadIdx.x >> 6);
    int lane = threadIdx.x & 63;
    if (gw >= N_COLS) return;
    const float* row = (gw < B_ROWS) ? orig + (size_t)gw * D_DIM
                                     : masked + (size_t)(gw - B_ROWS) * D_DIM;
    float4 a = *(const float4*)(row + lane * 4);        // floats [0,256)
    float4 b = *(const float4*)(row + 256 + lane * 4);  // floats [256,512)
    float s = a.x*a.x + a.y*a.y + a.z*a.z + a.w*a.w
            + b.x*b.x + b.y*b.y + b.z*b.z + b.w*b.w;
    #pragma unroll
    for (int off = 32; off >= 1; off >>= 1) s += __shfl_xor(s, off, 64);
    if (lane == 0) inv[gw] = 1.0f / fmaxf(sqrtf(s), 1e-12f);
}

// Fused sim-GEMM + exp + row-sum. Each block: BM rows x CHUNK cols.
__global__ __launch_bounds__(256, 4) void simexp_kernel(
        const float* __restrict__ orig, const float* __restrict__ masked,
        const float* __restrict__ inv, const int* __restrict__ itp,
        float* __restrict__ denom, float* __restrict__ pos) {
    __shared__ float As[BK][BM];   // K-major: As[k][m] = A[rowBase+m][kb+k]
    __shared__ float Bs[BK][BN];   // K-major: Bs[k][n] = allemb[colBase+n][kb+k]
    __shared__ float invc[BN];

    const float invT = inv_temp(itp);
    const int rowBase = blockIdx.y * BM;
    const int colStart = blockIdx.x * CHUNK;

    const int tid = threadIdx.x;
    const int tx = tid & 15;   // col group: cols tx*8 .. tx*8+7
    const int ty = tid >> 4;   // row group: rows ty*8 .. ty*8+7

    float invr[8];
    #pragma unroll
    for (int r = 0; r < 8; ++r) invr[r] = inv[rowBase + ty * 8 + r] * invT;

    float denomLoc[8] = {0.f, 0.f, 0.f, 0.f, 0.f, 0.f, 0.f, 0.f};

    for (int t = 0; t < CHUNK / BN; ++t) {
        const int colBase = colStart + t * BN;
        // all_emb rows: [0,B) -> orig, [B,N) -> masked (contiguous [M*B, D])
        const float* bsrc = (colBase < B_ROWS)
                          ? orig + (size_t)colBase * D_DIM
                          : masked + (size_t)(colBase - B_ROWS) * D_DIM;

        __syncthreads();                       // protect invc from prev epilogue readers
        if (tid < BN) invc[tid] = inv[colBase + tid];

        float acc[8][8];
        #pragma unroll
        for (int r = 0; r < 8; ++r)
            #pragma unroll
            for (int c = 0; c < 8; ++c) acc[r][c] = 0.f;

        for (int kb = 0; kb < D_DIM; kb += BK) {
            __syncthreads();                   // prev compute done before overwrite
            #pragma unroll
            for (int i = 0; i < 4; ++i) {      // A tile: 1024 float4, 4/thread
                int q = tid + 256 * i;
                int m = q >> 3;
                int kq = q & 7;
                float4 v = *(const float4*)(orig + (size_t)(rowBase + m) * D_DIM + kb + kq * 4);
                As[kq*4+0][m] = v.x; As[kq*4+1][m] = v.y;
                As[kq*4+2][m] = v.z; As[kq*4+3][m] = v.w;
            }
            #pragma unroll
            for (int i = 0; i < 4; ++i) {      // B tile
                int q = tid + 256 * i;
                int n = q >> 3;
                int kq = q & 7;
                float4 v = *(const float4*)(bsrc + (size_t)n * D_DIM + kb + kq * 4);
                Bs[kq*4+0][n] = v.x; Bs[kq*4+1][n] = v.y;
                Bs[kq*4+2][n] = v.z; Bs[kq*4+3][n] = v.w;
            }
            __syncthreads();

            #pragma unroll 4
            for (int k = 0; k < BK; ++k) {
                float4 a0 = *(const float4*)&As[k][ty*8];
                float4 a1 = *(const float4*)&As[k][ty*8+4];
                float4 b0 = *(const float4*)&Bs[k][tx*8];
                float4 b1 = *(const float4*)&Bs[k][tx*8+4];
                float av[8] = {a0.x,a0.y,a0.z,a0.w,a1.x,a1.y,a1.z,a1.w};
                float bv[8] = {b0.x,b0.y,b0.z,b0.w,b1.x,b1.y,b1.z,b1.w};
                #pragma unroll
                for (int r = 0; r < 8; ++r)
                    #pragma unroll
                    for (int c = 0; c < 8; ++c)
                        acc[r][c] = fmaf(av[r], bv[c], acc[r][c]);
            }
        }

        // Epilogue: sim = dot*inv_i*inv_j/T; diag masked to 0; accumulate exp.
        const bool diagTile = (colBase == rowBase);
        #pragma unroll
        for (int r = 0; r < 8; ++r) {
            const int row = rowBase + ty * 8 + r;
            #pragma unroll
            for (int c = 0; c < 8; ++c) {
                const int col = colBase + tx * 8 + c;
                float e = __expf(acc[r][c] * invr[r] * invc[tx*8+c]);
                if (diagTile && col == row) e = 0.f;
                denomLoc[r] += e;
                // positives: col = (m+1)*B + row, m in [0,M)
                if (col >= B_ROWS && ((col - row) & (B_ROWS - 1)) == 0)
                    atomicAdd(&pos[row], e);
            }
        }
    }

    // 16 lanes (same ty within a wave) share the same 8 rows -> shuffle reduce
    #pragma unroll
    for (int r = 0; r < 8; ++r) {
        #pragma unroll
        for (int off = 1; off < 16; off <<= 1)
            denomLoc[r] += __shfl_xor(denomLoc[r], off, 64);
    }
    if (tx == 0) {
        #pragma unroll
        for (int r = 0; r < 8; ++r)
            atomicAdd(&denom[rowBase + ty * 8 + r], denomLoc[r]);
    }
}

__global__ __launch_bounds__(256) void loss_kernel(
        const float* __restrict__ denom, const float* __restrict__ pos,
        float* __restrict__ out) {
    __shared__ double buf[256];
    double s = 0.0;
    for (int i = threadIdx.x; i < B_ROWS; i += 256) {
        float p = pos[i];
        float d = denom[i] + 1e-8f;
        s += (double)(-logf(p / d));
    }
    buf[threadIdx.x] = s;
    __syncthreads();
    for (int off = 128; off >= 1; off >>= 1) {
        if (threadIdx.x < off) buf[threadIdx.x] += buf[threadIdx.x + off];
        __syncthreads();
    }
    if (threadIdx.x == 0) out[0] = (float)(buf[0] / (double)B_ROWS);
}

extern "C" void kernel_launch(void* const* d_in, const int* in_sizes, int n_in,
                              void* d_out, int out_size, void* d_ws, size_t ws_size,
                              hipStream_t stream) {
    const float* orig   = (const float*)d_in[0];   // [B, D]
    const float* masked = (const float*)d_in[1];   // [M, B, D]
    const int*   itp    = (const int*)d_in[2];     // [1]

    float* inv   = (float*)d_ws;         // N_COLS floats
    float* denom = inv + N_COLS;         // B floats
    float* pos   = denom + B_ROWS;       // B floats (contiguous with denom)
    float* out   = (float*)d_out;

    // ws is re-poisoned to 0xAA before every launch -> zero the accumulators.
    hipMemsetAsync(denom, 0, 2 * B_ROWS * sizeof(float), stream);

    norm_kernel<<<N_COLS / 4, 256, 0, stream>>>(orig, masked, inv);

    dim3 grid(COLSPLIT, B_ROWS / BM);
    simexp_kernel<<<grid, 256, 0, stream>>>(orig, masked, inv, itp, denom, pos);

    loss_kernel<<<1, 256, 0, stream>>>(denom, pos, out);
}

// Round 3
// 294.863 us; speedup vs baseline: 3.9334x; 3.9334x over previous
//
#include <hip/hip_runtime.h>
#include <math.h>

// ADIOS contrastive loss, MI355X — split-fp16 MFMA version.
// x (fp32, normalized) == hi + lo with hi=fp16(x), lo=fp16(x-hi).
// GEMM over K=1024 ([hi|lo]) on matrix cores: hi*hi + lo*lo terms give
// ~1.5e-4 rel accuracy on exp(sim) (cross terms bounded ~3e-5 on unit dot).

#define B_ROWS 4096
#define M_MASK 4
#define D_DIM  512
#define N_COLS ((M_MASK + 1) * B_ROWS)   // 20480
#define GK     (2 * D_DIM)               // 1024 fp16 (hi | lo)

typedef _Float16 f16x8 __attribute__((ext_vector_type(8)));
typedef _Float16 f16x4 __attribute__((ext_vector_type(4)));
typedef float    f32x4 __attribute__((ext_vector_type(4)));

__device__ __forceinline__ float inv_temp(const int* __restrict__ itp) {
    int it = *itp;
    double T;
    if (it >= 300000) {
        T = 0.05;
    } else {
        double p = (double)it / 300000.0;
        T = 0.05 + 0.5 * (0.2 - 0.05) * (1.0 + cos(3.14159265358979323846 * p));
    }
    return (float)(1.0 / T);
}

// One wave per row: L2-normalize, split into fp16 hi/lo, store [N_COLS][GK].
__global__ __launch_bounds__(256) void prep_kernel(
        const float* __restrict__ orig, const float* __restrict__ masked,
        _Float16* __restrict__ E) {
    int gw = blockIdx.x * 4 + (threadIdx.x >> 6);
    int l  = threadIdx.x & 63;
    if (gw >= N_COLS) return;
    const float* row = (gw < B_ROWS) ? orig + (size_t)gw * D_DIM
                                     : masked + (size_t)(gw - B_ROWS) * D_DIM;
    float4 a = *(const float4*)(row + l * 4);        // elems [0,256)
    float4 b = *(const float4*)(row + 256 + l * 4);  // elems [256,512)
    float s = a.x*a.x + a.y*a.y + a.z*a.z + a.w*a.w
            + b.x*b.x + b.y*b.y + b.z*b.z + b.w*b.w;
    #pragma unroll
    for (int off = 1; off < 64; off <<= 1) s += __shfl_xor(s, off, 64);
    float inv = 1.0f / fmaxf(sqrtf(s), 1e-12f);

    float xa[4] = {a.x*inv, a.y*inv, a.z*inv, a.w*inv};
    float xb[4] = {b.x*inv, b.y*inv, b.z*inv, b.w*inv};
    f16x4 hiA, loA, hiB, loB;
    #pragma unroll
    for (int j = 0; j < 4; ++j) {
        hiA[j] = (_Float16)xa[j];  loA[j] = (_Float16)(xa[j] - (float)hiA[j]);
        hiB[j] = (_Float16)xb[j];  loB[j] = (_Float16)(xb[j] - (float)hiB[j]);
    }
    _Float16* er = E + (size_t)gw * GK;
    *(f16x4*)(er + l * 4)             = hiA;   // hi, k in [0,256)
    *(f16x4*)(er + 256 + l * 4)       = hiB;   // hi, k in [256,512)
    *(f16x4*)(er + 512 + l * 4)       = loA;   // lo, k in [0,256)
    *(f16x4*)(er + 768 + l * 4)       = loB;   // lo, k in [256,512)
}

// 128x128 tile MFMA GEMM (m97 structure) with fused exp/denom/pos epilogue.
// A = rows [0,4096) of E; B = all rows of E. sim = (A·B^T) * invT.
__global__ __launch_bounds__(256, 2) void gemm_kernel(
        const _Float16* __restrict__ E, const int* __restrict__ itp,
        float* __restrict__ denom, float* __restrict__ pos) {
    __shared__ _Float16 As[128 * 32];
    __shared__ _Float16 Bs[128 * 32];

    const int tid = threadIdx.x;
    const int l   = tid & 63;
    const int wid = tid >> 6;      // 4 waves: 2x2 over the 128x128 tile
    const int wr  = wid >> 1;      // wave row-half (64 rows)
    const int wc  = wid & 1;       // wave col-half (64 cols)

    const int rowTile = blockIdx.x & 31;     // 4096/128
    const int colTile = blockIdx.x >> 5;     // 20480/128
    const int rowBase = rowTile * 128;
    const int colBase = colTile * 128;

    const _Float16* Ag = E + (size_t)rowBase * GK;
    const _Float16* Bg = E + (size_t)colBase * GK;

    f32x4 acc[4][4];
    #pragma unroll
    for (int m = 0; m < 4; ++m)
        #pragma unroll
        for (int n = 0; n < 4; ++n)
            #pragma unroll
            for (int j = 0; j < 4; ++j) acc[m][n][j] = 0.f;

    for (int kb = 0; kb < GK; kb += 32) {
        __syncthreads();   // previous iter's frag reads done before overwrite
        #pragma unroll
        for (int i = 0; i < 2; ++i) {
            const int rc = wid * 32 + i * 16;             // 16-row chunk base
            const int r  = rc + (l >> 2);                 // this lane's row
            const size_t go = (size_t)r * GK + kb + (l & 3) * 8;
            __builtin_amdgcn_global_load_lds(
                (const __attribute__((address_space(1))) void*)(Ag + go),
                (__attribute__((address_space(3))) void*)&As[rc * 32], 16, 0, 0);
            __builtin_amdgcn_global_load_lds(
                (const __attribute__((address_space(1))) void*)(Bg + go),
                (__attribute__((address_space(3))) void*)&Bs[rc * 32], 16, 0, 0);
        }
        __syncthreads();   // loads visible

        f16x8 af[4], bf[4];
        #pragma unroll
        for (int m = 0; m < 4; ++m)
            af[m] = *(const f16x8*)&As[(wr * 64 + m * 16 + (l & 15)) * 32 + (l >> 4) * 8];
        #pragma unroll
        for (int n = 0; n < 4; ++n)
            bf[n] = *(const f16x8*)&Bs[(wc * 64 + n * 16 + (l & 15)) * 32 + (l >> 4) * 8];
        #pragma unroll
        for (int m = 0; m < 4; ++m)
            #pragma unroll
            for (int n = 0; n < 4; ++n)
                acc[m][n] = __builtin_amdgcn_mfma_f32_16x16x32_f16(af[m], bf[n], acc[m][n], 0, 0, 0);
    }

    // Epilogue: e = exp(acc*invT) (diag -> 0); row-sums + positives.
    const float scale = inv_temp(itp) * 1.44269504088896340736f;  // exp2
    float dsum[16];
    #pragma unroll
    for (int i = 0; i < 16; ++i) dsum[i] = 0.f;

    #pragma unroll
    for (int m = 0; m < 4; ++m) {
        #pragma unroll
        for (int n = 0; n < 4; ++n) {
            #pragma unroll
            for (int r = 0; r < 4; ++r) {
                const int row = rowBase + wr * 64 + m * 16 + (l >> 4) * 4 + r;
                const int col = colBase + wc * 64 + n * 16 + (l & 15);
                float e = exp2f(acc[m][n][r] * scale);
                if (col == row) e = 0.f;
                dsum[m * 4 + r] += e;
                const int d = col - row;
                if (d > 0 && (d & (B_ROWS - 1)) == 0) atomicAdd(&pos[row], e);
            }
        }
    }
    // reduce over the 16 lanes sharing the same row set (l>>4 fixed)
    #pragma unroll
    for (int i = 0; i < 16; ++i) {
        #pragma unroll
        for (int off = 1; off < 16; off <<= 1)
            dsum[i] += __shfl_xor(dsum[i], off, 64);
    }
    if ((l & 15) == 0) {
        #pragma unroll
        for (int i = 0; i < 16; ++i) {
            const int row = rowBase + wr * 64 + (i >> 2) * 16 + (l >> 4) * 4 + (i & 3);
            atomicAdd(&denom[row], dsum[i]);
        }
    }
}

__global__ __launch_bounds__(256) void loss_kernel(
        const float* __restrict__ denom, const float* __restrict__ pos,
        float* __restrict__ out) {
    __shared__ double buf[256];
    double s = 0.0;
    for (int i = threadIdx.x; i < B_ROWS; i += 256) {
        float p = pos[i];
        float d = denom[i] + 1e-8f;
        s += (double)(-logf(p / d));
    }
    buf[threadIdx.x] = s;
    __syncthreads();
    for (int off = 128; off >= 1; off >>= 1) {
        if (threadIdx.x < off) buf[threadIdx.x] += buf[threadIdx.x + off];
        __syncthreads();
    }
    if (threadIdx.x == 0) out[0] = (float)(buf[0] / (double)B_ROWS);
}

extern "C" void kernel_launch(void* const* d_in, const int* in_sizes, int n_in,
                              void* d_out, int out_size, void* d_ws, size_t ws_size,
                              hipStream_t stream) {
    const float* orig   = (const float*)d_in[0];   // [B, D]
    const float* masked = (const float*)d_in[1];   // [M, B, D]
    const int*   itp    = (const int*)d_in[2];     // [1]

    _Float16* E   = (_Float16*)d_ws;                       // [N_COLS][GK] ~40 MB
    float* denom  = (float*)(E + (size_t)N_COLS * GK);     // [B]
    float* pos    = denom + B_ROWS;                        // [B]
    float* out    = (float*)d_out;

    hipMemsetAsync(denom, 0, 2 * B_ROWS * sizeof(float), stream);

    prep_kernel<<<N_COLS / 4, 256, 0, stream>>>(orig, masked, E);

    gemm_kernel<<<(B_ROWS / 128) * (N_COLS / 128), 256, 0, stream>>>(E, itp, denom, pos);

    loss_kernel<<<1, 256, 0, stream>>>(denom, pos, out);
}

// Round 6
// 212.178 us; speedup vs baseline: 5.4663x; 1.3897x over previous
//
#include <hip/hip_runtime.h>
#include <math.h>

// ADIOS contrastive loss, MI355X — fp16-hi MFMA version (K=512).
// Normalized embeddings cast to fp16; dot error is the hi/lo cross terms
// (~2e-5 on a unit dot) — identical to the previous [hi|lo] K=1024 scheme,
// whose lo*lo term contributed only ~1e-10. Half the FLOPs, same accuracy.

#define B_ROWS 4096
#define M_MASK 4
#define D_DIM  512
#define N_COLS ((M_MASK + 1) * B_ROWS)   // 20480
#define GK     D_DIM                     // 512 fp16

typedef _Float16 f16x8 __attribute__((ext_vector_type(8)));
typedef float    f32x4 __attribute__((ext_vector_type(4)));

__device__ __forceinline__ float inv_temp(const int* __restrict__ itp) {
    int it = *itp;
    double T;
    if (it >= 300000) {
        T = 0.05;
    } else {
        double p = (double)it / 300000.0;
        T = 0.05 + 0.5 * (0.2 - 0.05) * (1.0 + cos(3.14159265358979323846 * p));
    }
    return (float)(1.0 / T);
}

// One wave per row: L2-normalize, cast fp16, store [N_COLS][GK].
__global__ __launch_bounds__(256) void prep_kernel(
        const float* __restrict__ orig, const float* __restrict__ masked,
        _Float16* __restrict__ E) {
    int gw = blockIdx.x * 4 + (threadIdx.x >> 6);
    int l  = threadIdx.x & 63;
    if (gw >= N_COLS) return;
    const float* row = (gw < B_ROWS) ? orig + (size_t)gw * D_DIM
                                     : masked + (size_t)(gw - B_ROWS) * D_DIM;
    float4 a = *(const float4*)(row + l * 8);        // elems 8l..8l+3
    float4 b = *(const float4*)(row + l * 8 + 4);    // elems 8l+4..8l+7
    float s = a.x*a.x + a.y*a.y + a.z*a.z + a.w*a.w
            + b.x*b.x + b.y*b.y + b.z*b.z + b.w*b.w;
    #pragma unroll
    for (int off = 1; off < 64; off <<= 1) s += __shfl_xor(s, off, 64);
    float inv = 1.0f / fmaxf(sqrtf(s), 1e-12f);

    f16x8 h;
    h[0] = (_Float16)(a.x*inv); h[1] = (_Float16)(a.y*inv);
    h[2] = (_Float16)(a.z*inv); h[3] = (_Float16)(a.w*inv);
    h[4] = (_Float16)(b.x*inv); h[5] = (_Float16)(b.y*inv);
    h[6] = (_Float16)(b.z*inv); h[7] = (_Float16)(b.w*inv);
    *(f16x8*)(E + (size_t)gw * GK + l * 8) = h;
}

// 128x128 tile MFMA GEMM (m97 structure) with fused exp/denom/pos epilogue.
// A = rows [0,4096) of E; B = all rows of E. sim = (A·B^T) * invT.
__global__ __launch_bounds__(256, 2) void gemm_kernel(
        const _Float16* __restrict__ E, const int* __restrict__ itp,
        float* __restrict__ denom, float* __restrict__ pos) {
    __shared__ _Float16 As[128 * 32];
    __shared__ _Float16 Bs[128 * 32];

    const int tid = threadIdx.x;
    const int l   = tid & 63;
    const int wid = tid >> 6;      // 4 waves: 2x2 over the 128x128 tile
    const int wr  = wid >> 1;      // wave row-half (64 rows)
    const int wc  = wid & 1;       // wave col-half (64 cols)

    const int rowTile = blockIdx.x & 31;     // 4096/128
    const int colTile = blockIdx.x >> 5;     // 20480/128
    const int rowBase = rowTile * 128;
    const int colBase = colTile * 128;

    const _Float16* Ag = E + (size_t)rowBase * GK;
    const _Float16* Bg = E + (size_t)colBase * GK;

    f32x4 acc[4][4];
    #pragma unroll
    for (int m = 0; m < 4; ++m)
        #pragma unroll
        for (int n = 0; n < 4; ++n)
            #pragma unroll
            for (int j = 0; j < 4; ++j) acc[m][n][j] = 0.f;

    for (int kb = 0; kb < GK; kb += 32) {
        __syncthreads();   // previous iter's frag reads done before overwrite
        #pragma unroll
        for (int i = 0; i < 2; ++i) {
            const int rc = wid * 32 + i * 16;             // 16-row chunk base
            const int r  = rc + (l >> 2);                 // this lane's row
            const size_t go = (size_t)r * GK + kb + (l & 3) * 8;
            __builtin_amdgcn_global_load_lds(
                (const __attribute__((address_space(1))) void*)(Ag + go),
                (__attribute__((address_space(3))) void*)&As[rc * 32], 16, 0, 0);
            __builtin_amdgcn_global_load_lds(
                (const __attribute__((address_space(1))) void*)(Bg + go),
                (__attribute__((address_space(3))) void*)&Bs[rc * 32], 16, 0, 0);
        }
        __syncthreads();   // loads visible

        f16x8 af[4], bf[4];
        #pragma unroll
        for (int m = 0; m < 4; ++m)
            af[m] = *(const f16x8*)&As[(wr * 64 + m * 16 + (l & 15)) * 32 + (l >> 4) * 8];
        #pragma unroll
        for (int n = 0; n < 4; ++n)
            bf[n] = *(const f16x8*)&Bs[(wc * 64 + n * 16 + (l & 15)) * 32 + (l >> 4) * 8];
        #pragma unroll
        for (int m = 0; m < 4; ++m)
            #pragma unroll
            for (int n = 0; n < 4; ++n)
                acc[m][n] = __builtin_amdgcn_mfma_f32_16x16x32_f16(af[m], bf[n], acc[m][n], 0, 0, 0);
    }

    // Epilogue: e = exp(acc*invT) (diag -> 0); row-sums + positives.
    const float scale = inv_temp(itp) * 1.44269504088896340736f;  // exp2
    float dsum[16];
    #pragma unroll
    for (int i = 0; i < 16; ++i) dsum[i] = 0.f;

    #pragma unroll
    for (int m = 0; m < 4; ++m) {
        #pragma unroll
        for (int n = 0; n < 4; ++n) {
            #pragma unroll
            for (int r = 0; r < 4; ++r) {
                const int row = rowBase + wr * 64 + m * 16 + (l >> 4) * 4 + r;
                const int col = colBase + wc * 64 + n * 16 + (l & 15);
                float e = exp2f(acc[m][n][r] * scale);
                if (col == row) e = 0.f;
                dsum[m * 4 + r] += e;
                const int d = col - row;
                if (d > 0 && (d & (B_ROWS - 1)) == 0) atomicAdd(&pos[row], e);
            }
        }
    }
    // reduce over the 16 lanes sharing the same row set (l>>4 fixed)
    #pragma unroll
    for (int i = 0; i < 16; ++i) {
        #pragma unroll
        for (int off = 1; off < 16; off <<= 1)
            dsum[i] += __shfl_xor(dsum[i], off, 64);
    }
    if ((l & 15) == 0) {
        #pragma unroll
        for (int i = 0; i < 16; ++i) {
            const int row = rowBase + wr * 64 + (i >> 2) * 16 + (l >> 4) * 4 + (i & 3);
            atomicAdd(&denom[row], dsum[i]);
        }
    }
}

__global__ __launch_bounds__(256) void loss_kernel(
        const float* __restrict__ denom, const float* __restrict__ pos,
        float* __restrict__ out) {
    __shared__ double buf[256];
    double s = 0.0;
    for (int i = threadIdx.x; i < B_ROWS; i += 256) {
        float p = pos[i];
        float d = denom[i] + 1e-8f;
        s += (double)(-logf(p / d));
    }
    buf[threadIdx.x] = s;
    __syncthreads();
    for (int off = 128; off >= 1; off >>= 1) {
        if (threadIdx.x < off) buf[threadIdx.x] += buf[threadIdx.x + off];
        __syncthreads();
    }
    if (threadIdx.x == 0) out[0] = (float)(buf[0] / (double)B_ROWS);
}

extern "C" void kernel_launch(void* const* d_in, const int* in_sizes, int n_in,
                              void* d_out, int out_size, void* d_ws, size_t ws_size,
                              hipStream_t stream) {
    const float* orig   = (const float*)d_in[0];   // [B, D]
    const float* masked = (const float*)d_in[1];   // [M, B, D]
    const int*   itp    = (const int*)d_in[2];     // [1]

    _Float16* E   = (_Float16*)d_ws;                       // [N_COLS][GK] ~20 MB
    float* denom  = (float*)(E + (size_t)N_COLS * GK);     // [B]
    float* pos    = denom + B_ROWS;                        // [B]
    float* out    = (float*)d_out;

    hipMemsetAsync(denom, 0, 2 * B_ROWS * sizeof(float), stream);

    prep_kernel<<<N_COLS / 4, 256, 0, stream>>>(orig, masked, E);

    gemm_kernel<<<(B_ROWS / 128) * (N_COLS / 128), 256, 0, stream>>>(E, itp, denom, pos);

    loss_kernel<<<1, 256, 0, stream>>>(denom, pos, out);
}